// Round 7
// baseline (1801.556 us; speedup 1.0000x reference)
//
#include <hip/hip_runtime.h>

#define B_ 128
#define D_ 512
#define T_ 33
#define L_ 32
#define V_ 10000
#define NWG 128
#define NHELP 128
#define THREADS 512
#define NTILE_M 32
#define NTILE_N 79

typedef short short8 __attribute__((ext_vector_type(8)));
typedef float f32x4 __attribute__((ext_vector_type(4)));
typedef unsigned uint32x4 __attribute__((ext_vector_type(4)));
typedef unsigned uint32x2 __attribute__((ext_vector_type(2)));

__device__ __forceinline__ short f2bf_rne(float f) {
    unsigned u = __builtin_bit_cast(unsigned, f);
    unsigned r = (u + 0x7FFFu + ((u >> 16) & 1u)) >> 16;
    return (short)r;
}
// truncation split: v ~= hi + lo with ~17 mantissa bits total
__device__ __forceinline__ void split2(float v, short& hi, short& lo) {
    unsigned u = __builtin_bit_cast(unsigned, v);
    hi = (short)(u >> 16);
    float hif = __builtin_bit_cast(float, u & 0xFFFF0000u);
    lo = (short)(__builtin_bit_cast(unsigned, v - hif) >> 16);
}
__device__ __forceinline__ float sigm(float x) {
    return 1.0f / (1.0f + __expf(-x));
}
__device__ __forceinline__ float unpack2f(unsigned u) {
    return __builtin_bit_cast(float, u << 16)
         + __builtin_bit_cast(float, u & 0xFFFF0000u);
}

// LLC-coherent store (sc0+sc1: write-through past L1/L2; no wbl2 needed).
__device__ __forceinline__ void llc_stu(void* p, unsigned v) {
    __hip_atomic_store((unsigned*)p, v, __ATOMIC_RELAXED,
                       __HIP_MEMORY_SCOPE_SYSTEM);
}
// LLC-coherent vector loads (sc0+sc1 bypass L1/L2 -> read at the coherence
// point, NO acquire fence / buffer_inv required anywhere). Issue-many then
// llc_wait() once: loads pipeline, one exposed latency per batch.
__device__ __forceinline__ uint32x4 llc_ld4(const void* p) {
    uint32x4 r;
    asm volatile("global_load_dwordx4 %0, %1, off sc0 sc1"
                 : "=v"(r) : "v"(p));
    return r;
}
__device__ __forceinline__ uint32x2 llc_ld2(const void* p) {
    uint32x2 r;
    asm volatile("global_load_dwordx2 %0, %1, off sc0 sc1"
                 : "=v"(r) : "v"(p));
    return r;
}
// rule #18: sched_barrier(0) right after the waitcnt so the compiler cannot
// hoist register-only consumers above the wait.
__device__ __forceinline__ void llc_wait() {
    asm volatile("s_waitcnt vmcnt(0)" ::: "memory");
    __builtin_amdgcn_sched_barrier(0);
}

// ---------------------------------------------------------------------------
// prep: split X (features|emb) into hi/lo bf16, fc_W -> bf16 (RNE), zero flags
// ---------------------------------------------------------------------------
__global__ void prep_kernel(const float* __restrict__ features,
                            const int* __restrict__ caption,
                            const float* __restrict__ embW,
                            const float* __restrict__ fcW,
                            short* __restrict__ Xhi,
                            short* __restrict__ Xlo,
                            short* __restrict__ fcWb,
                            int* __restrict__ syncv) {
    const long NX = (long)T_ * B_ * D_;          // 2,162,688
    const long NW = (long)V_ * D_;               // 5,120,000
    const long total = NX + NW;
    long gid = (long)blockIdx.x * blockDim.x + threadIdx.x;
    if (gid < NWG) syncv[gid] = 0;               // arrival flags
    for (long idx = gid; idx < total; idx += (long)gridDim.x * blockDim.x) {
        if (idx < NX) {
            int t = (int)(idx / (B_ * D_));
            int r = (int)(idx % (B_ * D_));
            int b = r >> 9;
            int d = r & 511;
            float v;
            if (t == 0) v = features[r];
            else        v = embW[(long)caption[b * L_ + (t - 1)] * D_ + d];
            short hi, lo;
            split2(v, hi, lo);
            Xhi[idx] = hi;
            Xlo[idx] = lo;
        } else {
            long j = idx - NX;
            fcWb[j] = f2bf_rne(fcW[j]);
        }
    }
}

// ---------------------------------------------------------------------------
// Fused persistent kernel, grid = NWG + NHELP WGs x 512 threads:
//   blockIdx <  128 : persistent LSTM (148 KB LDS -> exactly 1 per CU)
//   blockIdx >= 128 : FC-GEMM helper WGs on the remaining 128 CUs, consuming
//                     Hnb slots as the LSTM publishes them (poll flag array).
//
// LSTM: split-bf16 MFMA (hi/lo x3), WG w owns d-cols [4w,4w+4), both layers.
// Deferred LayerNorm on the accumulator (gamma folded into Whh0; Sg/bconst
// precomputed). ALL cross-step global reads/writes are sc0+sc1 (LLC-coherent)
// -> zero cache-maintenance ops in the loop; X/weights stay L2-resident.
// Barrier: flag-array, arrive = syncthreads (vmcnt0 drain) + relaxed system
// store; wait = wave-0 gather of 128 flags + __all; no fence.
// Slot s of Hnb is published at flag value 2s+5 (epilogue slot 31 at 67 via
// one extra arrive).
// ---------------------------------------------------------------------------
__global__ __launch_bounds__(THREADS)
void lstm_persist(const short* __restrict__ Xhi, const short* __restrict__ Xlo,
                  const float* __restrict__ Wih, const float* __restrict__ Whh,
                  const float* __restrict__ bih, const float* __restrict__ bhh,
                  const float* __restrict__ lng, const float* __restrict__ lnb,
                  unsigned* __restrict__ H0p, unsigned* __restrict__ H1p,
                  short* __restrict__ Hnb, int* __restrict__ syncv,
                  const short* __restrict__ fcWb, const float* __restrict__ fcb,
                  float* __restrict__ out) {
    __shared__ __align__(16) short Wh[2][16][1032];   // 66 KB (hi)
    __shared__ __align__(16) short Wo[2][16][1032];   // 66 KB (lo)
    __shared__ float gbuf[128][17];
    __shared__ float carr[128][4];
    __shared__ float rs_s[128], murs_s[128];
    __shared__ float gam_s[512], bet_s[512];
    __shared__ float bias_s[2][16];
    __shared__ float bconst_s[16];
    __shared__ float sgam_s[16];

    const int tid  = threadIdx.x;
    const int wave = tid >> 6;
    const int lane = tid & 63;
    int* flags = syncv;

    // ======================= FC-GEMM helper path =======================
    if (blockIdx.x >= NWG) {
        const int h = blockIdx.x - NWG;
        // alias staging buffers into the (unused) weight LDS
        short* As = (short*)&Wh[0][0][0];   // [2][128][40] shorts = 20480 B
        short* Bs = As + 2 * 128 * 40;      // another 20480 B (fits in Wh)
        const int lrow  = tid >> 2;          // 0..127
        const int lcol  = (tid & 3) * 8;     // 0,8,16,24 shorts
        const int wavem = (wave >> 2) * 64;  // 0 / 64
        const int waven = (wave & 3) * 32;   // 0,32,64,96
        const int rsel  = lane & 15;
        const int kcol  = (lane >> 4) * 8;
        const int rquad = (lane >> 4) * 4;
        const int ncol  = lane & 15;

        for (int tau = h; tau < NTILE_M * NTILE_N; tau += NHELP) {
            const int mt = tau / NTILE_N;
            const int nt = tau - mt * NTILE_N;
            const int m0 = mt * 128, n0 = nt * 128;
            // wait for Hnb slot mt
            if (wave == 0) {
                const int tgt = 2 * mt + 5;
                int it2 = 0;
                for (;;) {
                    int f0 = __hip_atomic_load(&flags[lane], __ATOMIC_RELAXED,
                                               __HIP_MEMORY_SCOPE_SYSTEM);
                    int f1 = __hip_atomic_load(&flags[64 + lane], __ATOMIC_RELAXED,
                                               __HIP_MEMORY_SCOPE_SYSTEM);
                    if (__all(f0 >= tgt && f1 >= tgt)) break;
                    if (++it2 > (1 << 20)) break;   // safety net
                    __builtin_amdgcn_s_sleep(8);
                }
            }
            __syncthreads();

            f32x4 acc[4][2];
            #pragma unroll
            for (int i = 0; i < 4; ++i)
                #pragma unroll
                for (int j = 0; j < 2; ++j)
                    acc[i][j] = (f32x4){0.f, 0.f, 0.f, 0.f};

            const short* Ab = Hnb + (long)(m0 + lrow) * D_ + lcol;
            const int nrow = n0 + lrow;
            const short* Bb = fcWb + (long)nrow * D_ + lcol;
            const bool bok = nrow < V_;

            uint32x4 va = llc_ld4(Ab);
            uint32x4 vb = 0;
            if (bok) vb = llc_ld4(Bb);
            llc_wait();
            *(uint32x4*)&As[lrow * 40 + lcol] = va;
            *(uint32x4*)&Bs[lrow * 40 + lcol] = vb;
            uint32x4 va2 = llc_ld4(Ab + 32);
            uint32x4 vb2 = 0;
            if (bok) vb2 = llc_ld4(Bb + 32);
            __syncthreads();

            for (int kc = 0; kc < 16; ++kc) {
                const int bo = (kc & 1) * 5120;
                short8 a[4], bw[2];
                #pragma unroll
                for (int i = 0; i < 4; ++i)
                    a[i] = *(const short8*)&As[bo + (wavem + i * 16 + rsel) * 40 + kcol];
                #pragma unroll
                for (int j = 0; j < 2; ++j)
                    bw[j] = *(const short8*)&Bs[bo + (waven + j * 16 + rsel) * 40 + kcol];
                #pragma unroll
                for (int i = 0; i < 4; ++i)
                    #pragma unroll
                    for (int j = 0; j < 2; ++j)
                        acc[i][j] = __builtin_amdgcn_mfma_f32_16x16x32_bf16(a[i], bw[j], acc[i][j], 0, 0, 0);
                if (kc + 1 < 16) {
                    llc_wait();
                    const int b1 = ((kc + 1) & 1) * 5120;
                    *(uint32x4*)&As[b1 + lrow * 40 + lcol] = va2;
                    *(uint32x4*)&Bs[b1 + lrow * 40 + lcol] = vb2;
                    if (kc + 2 < 16) {
                        va2 = llc_ld4(Ab + (kc + 2) * 32);
                        vb2 = 0;
                        if (bok) vb2 = llc_ld4(Bb + (kc + 2) * 32);
                    }
                }
                __syncthreads();
            }

            #pragma unroll
            for (int i = 0; i < 4; ++i) {
                #pragma unroll
                for (int j = 0; j < 2; ++j) {
                    const int ngl = n0 + waven + j * 16 + ncol;
                    if (ngl < V_) {
                        const float bv = fcb[ngl];
                        #pragma unroll
                        for (int r = 0; r < 4; ++r) {
                            const int mgl = m0 + wavem + i * 16 + rquad + r;
                            const int tt = mgl >> 7;
                            const int bb = mgl & 127;
                            out[((long)bb * L_ + tt) * V_ + ngl] = acc[i][j][r] + bv;
                        }
                    }
                }
            }
        }
        return;
    }

    // ======================= LSTM path =======================
    const int w  = blockIdx.x;
    const int d0 = w * 4;
    const int wm = wave * 16;            // 8 waves x 16 rows
    const int n  = lane & 15;
    const int kq = (lane >> 4) * 8;

    // ---------------- preload ----------------
    gam_s[tid & 511] = lng[tid & 511];
    bet_s[tid & 511] = lnb[tid & 511];
    if (tid < 32) {
        int l = tid >> 4, nn = tid & 15;
        int row = (nn >> 2) * 512 + d0 + (nn & 3);
        bias_s[l][nn] = bih[l * 2048 + row] + bhh[l * 2048 + row];
    }
    for (int idx = tid; idx < 2 * 16 * 1024; idx += THREADS) {
        int l = idx >> 14;
        int nn = (idx >> 10) & 15;
        int k = idx & 1023;
        int row = (nn >> 2) * 512 + d0 + (nn & 3);
        float v = (k < 512) ? Wih[((long)(l * 2048 + row)) * 512 + k]
                            : Whh[((long)(l * 2048 + row)) * 512 + (k - 512)];
        if (l == 0 && k >= 512) v *= lng[k - 512];   // fold gamma into Whh0
        short hi, lo;
        split2(v, hi, lo);
        Wh[l][nn][k] = hi;
        Wo[l][nn][k] = lo;
    }
    if (tid < 256) {
        const int c = tid >> 4, kc = tid & 15;
        const int row = (c >> 2) * 512 + d0 + (c & 3);
        float sb = 0.f, sg = 0.f;
        for (int k = kc * 32; k < kc * 32 + 32; ++k) {
            const float wv = Whh[(long)row * 512 + k];
            sb += lnb[k] * wv;
            sg += lng[k] * wv;
        }
        gbuf[c][kc]      = sb;
        gbuf[64 + c][kc] = sg;
    }
    carr[tid >> 2][tid & 3] = 0.f;
    __syncthreads();
    if (tid < 32) {
        const int c = tid & 15;
        const int base = (tid >= 16) ? 64 + c : c;
        float s = 0.f;
        for (int i = 0; i < 16; ++i) s += gbuf[base][i];
        if (tid < 16) bconst_s[c] = s;
        else          sgam_s[c]   = s;
    }
    __syncthreads();

    int nb = 0;

    auto arrive = [&]() {
        __syncthreads();         // vmcnt0 drain of all waves' LLC stores
        ++nb;
        if (tid == 0)
            __hip_atomic_store(&flags[w], nb, __ATOMIC_RELAXED,
                               __HIP_MEMORY_SCOPE_SYSTEM);
    };
    auto wait_bar = [&]() {
        if (wave == 0) {
            const int tgt = nb;
            int iter = 0;
            for (;;) {
                int f0 = __hip_atomic_load(&flags[lane], __ATOMIC_RELAXED,
                                           __HIP_MEMORY_SCOPE_SYSTEM);
                int f1 = __hip_atomic_load(&flags[64 + lane], __ATOMIC_RELAXED,
                                           __HIP_MEMORY_SCOPE_SYSTEM);
                if (__all(f0 >= tgt && f1 >= tgt)) break;
                if (++iter > 65536) break;   // safety net
                __builtin_amdgcn_s_sleep(1);
            }
        }
        __syncthreads();         // no fence: all cross-step reads are sc0+sc1
    };

    // LN row stats from packed H1p via pipelined LLC loads (4 threads/row)
    auto ln_stats = [&]() {
        const int row = tid & 127, q = tid >> 7;
        const unsigned* hp = &H1p[row * 512 + q * 128];
        float s = 0.f, s2 = 0.f;
        #pragma unroll
        for (int c = 0; c < 2; ++c) {
            uint32x4 sb[16];
            #pragma unroll
            for (int i = 0; i < 16; ++i)
                sb[i] = llc_ld4(hp + c * 64 + i * 4);
            llc_wait();
            #pragma unroll
            for (int i = 0; i < 16; ++i) {
                #pragma unroll
                for (int e = 0; e < 4; ++e) {
                    const float v = unpack2f(sb[i][e]);
                    s  += v;
                    s2 += v * v;
                }
            }
        }
        gbuf[row][q * 2]     = s;
        gbuf[row][q * 2 + 1] = s2;
        __syncthreads();
        if (tid < 128) {
            const float ss  = gbuf[tid][0] + gbuf[tid][2] + gbuf[tid][4] + gbuf[tid][6];
            const float ss2 = gbuf[tid][1] + gbuf[tid][3] + gbuf[tid][5] + gbuf[tid][7];
            const float mu  = ss * (1.0f / 512.0f);
            const float var = ss2 * (1.0f / 512.0f) - mu * mu;
            const float rs  = rsqrtf(var + 1e-5f);
            rs_s[tid]   = rs;
            murs_s[tid] = mu * rs;
        }
        __syncthreads();
    };

    // materialize LN'd bf16 rows (4 rows for WGs 0..31) into Hnb slot
    unsigned* Hnb32 = (unsigned*)Hnb;
    auto mat_slot = [&](int slot) {
        const int rb = w * 4;
        const int p0 = tid, p1 = tid + 512;          // pair indices [0,1024)
        const int m0r = rb + (p0 >> 8), k0 = (p0 & 255) * 2;
        const int m1r = rb + (p1 >> 8), k1 = (p1 & 255) * 2;
        uint32x2 a = llc_ld2(&H1p[m0r * 512 + k0]);
        uint32x2 b = llc_ld2(&H1p[m1r * 512 + k1]);
        llc_wait();
        {
            const float v0 = unpack2f(a[0]), v1 = unpack2f(a[1]);
            const float o0 = fmaf(fmaf(v0, rs_s[m0r], -murs_s[m0r]), gam_s[k0],     bet_s[k0]);
            const float o1 = fmaf(fmaf(v1, rs_s[m0r], -murs_s[m0r]), gam_s[k0 + 1], bet_s[k0 + 1]);
            const unsigned pk = (unsigned)(unsigned short)f2bf_rne(o0)
                              | ((unsigned)(unsigned short)f2bf_rne(o1) << 16);
            llc_stu(&Hnb32[((long)slot * B_ + m0r) * 256 + (p0 & 255)], pk);
        }
        {
            const float v0 = unpack2f(b[0]), v1 = unpack2f(b[1]);
            const float o0 = fmaf(fmaf(v0, rs_s[m1r], -murs_s[m1r]), gam_s[k1],     bet_s[k1]);
            const float o1 = fmaf(fmaf(v1, rs_s[m1r], -murs_s[m1r]), gam_s[k1 + 1], bet_s[k1 + 1]);
            const unsigned pk = (unsigned)(unsigned short)f2bf_rne(o0)
                              | ((unsigned)(unsigned short)f2bf_rne(o1) << 16);
            llc_stu(&Hnb32[((long)slot * B_ + m1r) * 256 + (p1 & 255)], pk);
        }
    };

    const int rA0 = (wm + n) * 512;
    const int rq  = (lane >> 4) * 4;

    for (int t = 0; t < T_; ++t) {
        const short* xh = Xhi + (long)t * B_ * D_;
        const short* xl = Xlo + (long)t * B_ * D_;

        // ================= phase 0 (layer 0) =================
        {
            f32x4 accx = {0.f, 0.f, 0.f, 0.f};
            f32x4 acch = {0.f, 0.f, 0.f, 0.f};
            // x-half: L2-warm cached loads, runs while the barrier propagates
            #pragma unroll 4
            for (int kc = 0; kc < 16; ++kc) {
                const int kg = kc * 32 + kq;
                short8 bh = *(const short8*)&Wh[0][n][kg];
                short8 bl = *(const short8*)&Wo[0][n][kg];
                short8 ah = *(const short8*)&xh[rA0 + kg];
                short8 al = *(const short8*)&xl[rA0 + kg];
                accx = __builtin_amdgcn_mfma_f32_16x16x32_bf16(ah, bh, accx, 0, 0, 0);
                accx = __builtin_amdgcn_mfma_f32_16x16x32_bf16(ah, bl, accx, 0, 0, 0);
                accx = __builtin_amdgcn_mfma_f32_16x16x32_bf16(al, bh, accx, 0, 0, 0);
            }
            if (t > 0) {
                wait_bar();          // H1p(t-1) at the LLC
                // h-half on RAW packed h1, pipelined LLC loads (2 chunks)
                #pragma unroll
                for (int half = 0; half < 2; ++half) {
                    uint32x4 hb[16];
                    #pragma unroll
                    for (int i = 0; i < 8; ++i) {
                        const int kh = (half * 8 + i) * 32 + kq;
                        hb[i * 2]     = llc_ld4(&H1p[rA0 + kh]);
                        hb[i * 2 + 1] = llc_ld4(&H1p[rA0 + kh + 4]);
                    }
                    llc_wait();
                    #pragma unroll
                    for (int i = 0; i < 8; ++i) {
                        const int kh = (half * 8 + i) * 32 + kq;
                        short8 bh = *(const short8*)&Wh[0][n][512 + kh];
                        short8 bl = *(const short8*)&Wo[0][n][512 + kh];
                        unsigned u[8];
                        *(uint32x4*)&u[0] = hb[i * 2];
                        *(uint32x4*)&u[4] = hb[i * 2 + 1];
                        short8 ah, al;
                        #pragma unroll
                        for (int j = 0; j < 8; ++j) {
                            ah[j] = (short)(u[j] & 0xFFFFu);
                            al[j] = (short)(u[j] >> 16);
                        }
                        acch = __builtin_amdgcn_mfma_f32_16x16x32_bf16(ah, bh, acch, 0, 0, 0);
                        acch = __builtin_amdgcn_mfma_f32_16x16x32_bf16(ah, bl, acch, 0, 0, 0);
                        acch = __builtin_amdgcn_mfma_f32_16x16x32_bf16(al, bh, acch, 0, 0, 0);
                    }
                }
                ln_stats();          // rs_s/murs_s of h1(t-1)
                if (w < 32 && t >= 2) mat_slot(t - 2);
            }
            const float bs = bias_s[0][n] + (t > 0 ? bconst_s[n] : 0.f);
            const float sg = sgam_s[n];
            #pragma unroll
            for (int r = 0; r < 4; ++r) {
                const int row = wm + rq + r;
                float g = accx[r] + bs;
                if (t > 0) g += acch[r] * rs_s[row] - murs_s[row] * sg;
                gbuf[row][n] = g;
            }
            __syncthreads();
            {
                const int m = tid >> 2, d = tid & 3;
                const float gi = gbuf[m][d],     gf = gbuf[m][4 + d];
                const float gg = gbuf[m][8 + d], go = gbuf[m][12 + d];
                const float cn = sigm(gf) * carr[m][d] + sigm(gi) * tanhf(gg);
                carr[m][d] = cn;
                const float hv = sigm(go) * tanhf(cn);
                short hi_, lo_;
                split2(hv, hi_, lo_);
                const unsigned pk = (unsigned)(unsigned short)hi_
                                  | ((unsigned)(unsigned short)lo_ << 16);
                llc_stu(&H0p[m * 512 + d0 + d], pk);
            }
            arrive();   // barrier 2t+1: publish H0(t) (+ Hnb slot t-2)
        }

        // ================= phase 1 (layer 1) =================
        {
            f32x4 acc = {0.f, 0.f, 0.f, 0.f};
            #pragma unroll 4
            for (int kc = 0; kc < 16; ++kc) {
                const int kg = kc * 32 + kq;
                short8 bh = *(const short8*)&Wh[1][n][kg];
                short8 bl = *(const short8*)&Wo[1][n][kg];
                short8 ah = *(const short8*)&xh[rA0 + kg];
                short8 al = *(const short8*)&xl[rA0 + kg];
                acc = __builtin_amdgcn_mfma_f32_16x16x32_bf16(ah, bh, acc, 0, 0, 0);
                acc = __builtin_amdgcn_mfma_f32_16x16x32_bf16(ah, bl, acc, 0, 0, 0);
                acc = __builtin_amdgcn_mfma_f32_16x16x32_bf16(al, bh, acc, 0, 0, 0);
            }
            wait_bar();   // H0p(t) at the LLC
            #pragma unroll
            for (int half = 0; half < 2; ++half) {
                uint32x4 hb[16];
                #pragma unroll
                for (int i = 0; i < 8; ++i) {
                    const int kh = (half * 8 + i) * 32 + kq;
                    hb[i * 2]     = llc_ld4(&H0p[rA0 + kh]);
                    hb[i * 2 + 1] = llc_ld4(&H0p[rA0 + kh + 4]);
                }
                llc_wait();
                #pragma unroll
                for (int i = 0; i < 8; ++i) {
                    const int kh = (half * 8 + i) * 32 + kq;
                    short8 bh = *(const short8*)&Wh[1][n][512 + kh];
                    short8 bl = *(const short8*)&Wo[1][n][512 + kh];
                    unsigned u[8];
                    *(uint32x4*)&u[0] = hb[i * 2];
                    *(uint32x4*)&u[4] = hb[i * 2 + 1];
                    short8 ah, al;
                    #pragma unroll
                    for (int j = 0; j < 8; ++j) {
                        ah[j] = (short)(u[j] & 0xFFFFu);
                        al[j] = (short)(u[j] >> 16);
                    }
                    acc = __builtin_amdgcn_mfma_f32_16x16x32_bf16(ah, bh, acc, 0, 0, 0);
                    acc = __builtin_amdgcn_mfma_f32_16x16x32_bf16(ah, bl, acc, 0, 0, 0);
                    acc = __builtin_amdgcn_mfma_f32_16x16x32_bf16(al, bh, acc, 0, 0, 0);
                }
            }
            const float bs = bias_s[1][n];
            #pragma unroll
            for (int r = 0; r < 4; ++r)
                gbuf[wm + rq + r][n] = acc[r] + bs;
            __syncthreads();
            {
                const int m = tid >> 2, d = tid & 3;
                const float gi = gbuf[m][d],     gf = gbuf[m][4 + d];
                const float gg = gbuf[m][8 + d], go = gbuf[m][12 + d];
                const float cn = sigm(gf) * carr[m][d] + sigm(gi) * tanhf(gg);
                carr[m][d] = cn;
                const float hv = sigm(go) * tanhf(cn);
                short hi_, lo_;
                split2(hv, hi_, lo_);
                const unsigned pk = (unsigned)(unsigned short)hi_
                                  | ((unsigned)(unsigned short)lo_ << 16);
                llc_stu(&H1p[m * 512 + d0 + d], pk);   // RAW h1, packed
            }
            arrive();   // barrier 2t+2: publish H1p(t)
        }
    }

    // epilogue: final FC row block = LN(h1(T-1)) -> slot L_-1, then publish
    wait_bar();
    ln_stats();
    if (w < 32) mat_slot(L_ - 1);
    arrive();   // flags -> 67 = 2*31+5: unblocks helper tiles for slot 31
}

// ---------------------------------------------------------------------------
// log-softmax, 2 passes (|logits| <= ~35 so exp-sum is fp32-safe w/o shift)
// ---------------------------------------------------------------------------
__global__ void logsoftmax_kernel(float* __restrict__ out) {
    __shared__ float red[256];
    const long row = blockIdx.x;
    float* p = out + row * V_;
    float4* p4 = reinterpret_cast<float4*>(p);
    const int tid = threadIdx.x;
    float s = 0.f;
    for (int i = tid; i < V_ / 4; i += 256) {
        float4 v = p4[i];
        s += __expf(v.x) + __expf(v.y) + __expf(v.z) + __expf(v.w);
    }
    red[tid] = s;
    __syncthreads();
    for (int st = 128; st > 0; st >>= 1) {
        if (tid < st) red[tid] += red[tid + st];
        __syncthreads();
    }
    const float ls = logf(red[0]);
    for (int i = tid; i < V_ / 4; i += 256) {
        float4 v = p4[i];
        v.x -= ls; v.y -= ls; v.z -= ls; v.w -= ls;
        p4[i] = v;
    }
}

// ---------------------------------------------------------------------------
extern "C" void kernel_launch(void* const* d_in, const int* in_sizes, int n_in,
                              void* d_out, int out_size, void* d_ws, size_t ws_size,
                              hipStream_t stream) {
    const float* features = (const float*)d_in[0];
    const int*   caption  = (const int*)d_in[1];
    const float* embW     = (const float*)d_in[2];
    const float* W_ih     = (const float*)d_in[3];
    const float* W_hh     = (const float*)d_in[4];
    const float* b_ih     = (const float*)d_in[5];
    const float* b_hh     = (const float*)d_in[6];
    const float* ln_g     = (const float*)d_in[7];
    const float* ln_b     = (const float*)d_in[8];
    const float* fc_W     = (const float*)d_in[9];
    const float* fc_b     = (const float*)d_in[10];
    float* out = (float*)d_out;

    char* ws = (char*)d_ws;
    int*      syncv = (int*)ws;      ws += 512;                        // 128 flags
    short*    Xhi   = (short*)ws;    ws += (size_t)T_ * B_ * D_ * 2;   // 4,325,376
    short*    Xlo   = (short*)ws;    ws += (size_t)T_ * B_ * D_ * 2;
    unsigned* H0p   = (unsigned*)ws; ws += (size_t)B_ * D_ * 4;        // 262,144
    unsigned* H1p   = (unsigned*)ws; ws += (size_t)B_ * D_ * 4;        // 262,144
    short*    Hnb   = (short*)ws;    ws += (size_t)L_ * B_ * D_ * 2;   // 4,194,304
    short*    fcWb  = (short*)ws;    ws += (size_t)V_ * D_ * 2;        // 10,240,000

    prep_kernel<<<2048, 256, 0, stream>>>(features, caption, embW, fc_W,
                                          Xhi, Xlo, fcWb, syncv);

    lstm_persist<<<NWG + NHELP, THREADS, 0, stream>>>(
        Xhi, Xlo, W_ih, W_hh, b_ih, b_hh, ln_g, ln_b,
        H0p, H1p, Hnb, syncv, fcWb, fc_b, out);

    logsoftmax_kernel<<<4096, 256, 0, stream>>>(out);
}

// Round 8
// 1770.627 us; speedup vs baseline: 1.0175x; 1.0175x over previous
//
#include <hip/hip_runtime.h>

#define B_ 128
#define D_ 512
#define T_ 33
#define L_ 32
#define V_ 10000
#define NWG 128
#define NHELP 128
#define THREADS 512
#define NTILE_M 32
#define NTILE_N 79

typedef short short8 __attribute__((ext_vector_type(8)));
typedef float f32x4 __attribute__((ext_vector_type(4)));
typedef unsigned uint32x4 __attribute__((ext_vector_type(4)));
typedef unsigned uint32x2 __attribute__((ext_vector_type(2)));

__device__ __forceinline__ short f2bf_rne(float f) {
    unsigned u = __builtin_bit_cast(unsigned, f);
    unsigned r = (u + 0x7FFFu + ((u >> 16) & 1u)) >> 16;
    return (short)r;
}
// truncation split: v ~= hi + lo with ~17 mantissa bits total
__device__ __forceinline__ void split2(float v, short& hi, short& lo) {
    unsigned u = __builtin_bit_cast(unsigned, v);
    hi = (short)(u >> 16);
    float hif = __builtin_bit_cast(float, u & 0xFFFF0000u);
    lo = (short)(__builtin_bit_cast(unsigned, v - hif) >> 16);
}
__device__ __forceinline__ float sigm(float x) {
    return 1.0f / (1.0f + __expf(-x));
}
__device__ __forceinline__ float unpack2f(unsigned u) {
    return __builtin_bit_cast(float, u << 16)
         + __builtin_bit_cast(float, u & 0xFFFF0000u);
}

// LLC-coherent store (sc0+sc1 write-through; no wbl2 needed on writer side).
__device__ __forceinline__ void llc_stu(void* p, unsigned v) {
    __hip_atomic_store((unsigned*)p, v, __ATOMIC_RELAXED,
                       __HIP_MEMORY_SCOPE_SYSTEM);
}
// LLC-coherent vector loads (sc0+sc1 bypass L1/L2 -> coherent at the LLC, no
// acquire fence needed). Issue-many then one waitcnt: single exposed latency.
__device__ __forceinline__ uint32x4 llc_ld4(const void* p) {
    uint32x4 r;
    asm volatile("global_load_dwordx4 %0, %1, off sc0 sc1"
                 : "=v"(r) : "v"(p));
    return r;
}
__device__ __forceinline__ uint32x2 llc_ld2(const void* p) {
    uint32x2 r;
    asm volatile("global_load_dwordx2 %0, %1, off sc0 sc1"
                 : "=v"(r) : "v"(p));
    return r;
}
// rule #18: sched_barrier(0) right after a waitcnt so register-only consumers
// cannot be hoisted above it.
__device__ __forceinline__ void llc_wait0() {
    asm volatile("s_waitcnt vmcnt(0)" ::: "memory");
    __builtin_amdgcn_sched_barrier(0);
}
__device__ __forceinline__ void llc_wait16() {
    asm volatile("s_waitcnt vmcnt(16)" ::: "memory");
    __builtin_amdgcn_sched_barrier(0);
}

// ---------------------------------------------------------------------------
// prep: split X (features|emb) into hi/lo bf16, fc_W -> bf16 (RNE), zero flags
// ---------------------------------------------------------------------------
__global__ void prep_kernel(const float* __restrict__ features,
                            const int* __restrict__ caption,
                            const float* __restrict__ embW,
                            const float* __restrict__ fcW,
                            short* __restrict__ Xhi,
                            short* __restrict__ Xlo,
                            short* __restrict__ fcWb,
                            int* __restrict__ syncv) {
    const long NX = (long)T_ * B_ * D_;          // 2,162,688
    const long NW = (long)V_ * D_;               // 5,120,000
    const long total = NX + NW;
    long gid = (long)blockIdx.x * blockDim.x + threadIdx.x;
    if (gid < NWG) syncv[gid] = 0;               // arrival flags
    for (long idx = gid; idx < total; idx += (long)gridDim.x * blockDim.x) {
        if (idx < NX) {
            int t = (int)(idx / (B_ * D_));
            int r = (int)(idx % (B_ * D_));
            int b = r >> 9;
            int d = r & 511;
            float v;
            if (t == 0) v = features[r];
            else        v = embW[(long)caption[b * L_ + (t - 1)] * D_ + d];
            short hi, lo;
            split2(v, hi, lo);
            Xhi[idx] = hi;
            Xlo[idx] = lo;
        } else {
            long j = idx - NX;
            fcWb[j] = f2bf_rne(fcW[j]);
        }
    }
}

// ---------------------------------------------------------------------------
// Fused persistent kernel, grid = NWG + NHELP WGs x 512 threads:
//   blockIdx <  128 : persistent LSTM (148 KB LDS -> 1 per CU)
//   blockIdx >= 128 : FC-GEMM helpers on the other 128 CUs, consuming Hnb
//                     slots as published (flag 2s+5; epilogue slot 31 at 67).
//
// LSTM: split-bf16 MFMA, WG w owns d-cols [4w,4w+4), both layers. Deferred
// LayerNorm on the accumulator; LN stats computed INLINE during the h-half
// MFMA pass (wave covers all 512 cols of its 16 rows; shfl_xor 16/32 reduce)
// -> no separate stats read pass. h loads are 32-deep vmcnt-pipelined.
// Helpers: A (Hnb) via sc0+sc1 (intra-kernel coherence), B (fcWb) + bias via
// NORMAL cached loads (pre-dispatch data; L2-resident -> no LLC streaming).
// ---------------------------------------------------------------------------
__global__ __launch_bounds__(THREADS)
void lstm_persist(const short* __restrict__ Xhi, const short* __restrict__ Xlo,
                  const float* __restrict__ Wih, const float* __restrict__ Whh,
                  const float* __restrict__ bih, const float* __restrict__ bhh,
                  const float* __restrict__ lng, const float* __restrict__ lnb,
                  unsigned* __restrict__ H0p, unsigned* __restrict__ H1p,
                  short* __restrict__ Hnb, int* __restrict__ syncv,
                  const short* __restrict__ fcWb, const float* __restrict__ fcb,
                  float* __restrict__ out) {
    __shared__ __align__(16) short Wh[2][16][1032];   // 66 KB (hi)
    __shared__ __align__(16) short Wo[2][16][1032];   // 66 KB (lo)
    __shared__ float gbuf[128][17];
    __shared__ float carr[128][4];
    __shared__ float rs_s[128], murs_s[128];
    __shared__ float gam_s[512], bet_s[512];
    __shared__ float bias_s[2][16];
    __shared__ float bconst_s[16];
    __shared__ float sgam_s[16];

    const int tid  = threadIdx.x;
    const int wave = tid >> 6;
    const int lane = tid & 63;
    int* flags = syncv;

    // ======================= FC-GEMM helper path =======================
    if (blockIdx.x >= NWG) {
        const int h = blockIdx.x - NWG;
        short* As = (short*)&Wh[0][0][0];   // 2 x 128 x 40 shorts = 20480 B
        short* Bs = As + 2 * 128 * 40;      // 20480 B more (fits in Wh)
        const int lrow  = tid >> 2;          // 0..127
        const int lcol  = (tid & 3) * 8;     // 0,8,16,24 shorts
        const int wavem = (wave >> 2) * 64;  // 0 / 64
        const int waven = (wave & 3) * 32;   // 0,32,64,96
        const int rsel  = lane & 15;
        const int kcol  = (lane >> 4) * 8;
        const int rquad = (lane >> 4) * 4;
        const int ncol  = lane & 15;

        for (int tau = h; tau < NTILE_M * NTILE_N; tau += NHELP) {
            const int mt = tau / NTILE_N;
            const int nt = tau - mt * NTILE_N;
            const int m0 = mt * 128, n0 = nt * 128;
            // wait for Hnb slot mt (m-major tau order -> mt non-decreasing,
            // so this check is usually already satisfied)
            if (wave == 0) {
                const int tgt = 2 * mt + 5;
                int it2 = 0;
                for (;;) {
                    int f0 = __hip_atomic_load(&flags[lane], __ATOMIC_RELAXED,
                                               __HIP_MEMORY_SCOPE_SYSTEM);
                    int f1 = __hip_atomic_load(&flags[64 + lane], __ATOMIC_RELAXED,
                                               __HIP_MEMORY_SCOPE_SYSTEM);
                    if (__all(f0 >= tgt && f1 >= tgt)) break;
                    if (++it2 > (1 << 20)) break;   // safety net
                    __builtin_amdgcn_s_sleep(32);
                }
            }
            __syncthreads();

            f32x4 acc[4][2];
            #pragma unroll
            for (int i = 0; i < 4; ++i)
                #pragma unroll
                for (int j = 0; j < 2; ++j)
                    acc[i][j] = (f32x4){0.f, 0.f, 0.f, 0.f};

            const short* Ab = Hnb + (long)(m0 + lrow) * D_ + lcol;
            const int nrow = n0 + lrow;
            const short* Bb = fcWb + (long)nrow * D_ + lcol;
            const bool bok = nrow < V_;

            // stage kc=0 (A via LLC, B via cached loads)
            uint32x4 va = llc_ld4(Ab);
            uint32x4 vb = bok ? *(const uint32x4*)Bb : (uint32x4)0;
            llc_wait0();
            *(uint32x4*)&As[lrow * 40 + lcol] = va;
            *(uint32x4*)&Bs[lrow * 40 + lcol] = vb;
            uint32x4 va2 = llc_ld4(Ab + 32);
            uint32x4 vb2 = bok ? *(const uint32x4*)(Bb + 32) : (uint32x4)0;
            __syncthreads();

            for (int kc = 0; kc < 16; ++kc) {
                const int bo = (kc & 1) * 5120;
                short8 a[4], bw[2];
                #pragma unroll
                for (int i = 0; i < 4; ++i)
                    a[i] = *(const short8*)&As[bo + (wavem + i * 16 + rsel) * 40 + kcol];
                #pragma unroll
                for (int j = 0; j < 2; ++j)
                    bw[j] = *(const short8*)&Bs[bo + (waven + j * 16 + rsel) * 40 + kcol];
                #pragma unroll
                for (int i = 0; i < 4; ++i)
                    #pragma unroll
                    for (int j = 0; j < 2; ++j)
                        acc[i][j] = __builtin_amdgcn_mfma_f32_16x16x32_bf16(a[i], bw[j], acc[i][j], 0, 0, 0);
                if (kc + 1 < 16) {
                    llc_wait0();
                    const int b1 = ((kc + 1) & 1) * 5120;
                    *(uint32x4*)&As[b1 + lrow * 40 + lcol] = va2;
                    *(uint32x4*)&Bs[b1 + lrow * 40 + lcol] = vb2;
                    if (kc + 2 < 16) {
                        va2 = llc_ld4(Ab + (kc + 2) * 32);
                        vb2 = bok ? *(const uint32x4*)(Bb + (kc + 2) * 32) : (uint32x4)0;
                    }
                }
                __syncthreads();
            }

            #pragma unroll
            for (int i = 0; i < 4; ++i) {
                #pragma unroll
                for (int j = 0; j < 2; ++j) {
                    const int ngl = n0 + waven + j * 16 + ncol;
                    if (ngl < V_) {
                        const float bv = fcb[ngl];
                        #pragma unroll
                        for (int r = 0; r < 4; ++r) {
                            const int mgl = m0 + wavem + i * 16 + rquad + r;
                            const int tt = mgl >> 7;
                            const int bb = mgl & 127;
                            out[((long)bb * L_ + tt) * V_ + ngl] = acc[i][j][r] + bv;
                        }
                    }
                }
            }
        }
        return;
    }

    // ======================= LSTM path =======================
    const int w  = blockIdx.x;
    const int d0 = w * 4;
    const int wm = wave * 16;            // 8 waves x 16 rows
    const int n  = lane & 15;
    const int kq = (lane >> 4) * 8;

    // ---------------- preload ----------------
    gam_s[tid & 511] = lng[tid & 511];
    bet_s[tid & 511] = lnb[tid & 511];
    if (tid < 32) {
        int l = tid >> 4, nn = tid & 15;
        int row = (nn >> 2) * 512 + d0 + (nn & 3);
        bias_s[l][nn] = bih[l * 2048 + row] + bhh[l * 2048 + row];
    }
    for (int idx = tid; idx < 2 * 16 * 1024; idx += THREADS) {
        int l = idx >> 14;
        int nn = (idx >> 10) & 15;
        int k = idx & 1023;
        int row = (nn >> 2) * 512 + d0 + (nn & 3);
        float v = (k < 512) ? Wih[((long)(l * 2048 + row)) * 512 + k]
                            : Whh[((long)(l * 2048 + row)) * 512 + (k - 512)];
        if (l == 0 && k >= 512) v *= lng[k - 512];   // fold gamma into Whh0
        short hi, lo;
        split2(v, hi, lo);
        Wh[l][nn][k] = hi;
        Wo[l][nn][k] = lo;
    }
    if (tid < 256) {
        const int c = tid >> 4, kc = tid & 15;
        const int row = (c >> 2) * 512 + d0 + (c & 3);
        float sb = 0.f, sg = 0.f;
        for (int k = kc * 32; k < kc * 32 + 32; ++k) {
            const float wv = Whh[(long)row * 512 + k];
            sb += lnb[k] * wv;
            sg += lng[k] * wv;
        }
        gbuf[c][kc]      = sb;
        gbuf[64 + c][kc] = sg;
    }
    carr[tid >> 2][tid & 3] = 0.f;
    __syncthreads();
    if (tid < 32) {
        const int c = tid & 15;
        const int base = (tid >= 16) ? 64 + c : c;
        float s = 0.f;
        for (int i = 0; i < 16; ++i) s += gbuf[base][i];
        if (tid < 16) bconst_s[c] = s;
        else          sgam_s[c]   = s;
    }
    __syncthreads();

    int nb = 0;

    auto arrive = [&]() {
        __syncthreads();         // vmcnt0 drain of all waves' LLC stores
        ++nb;
        if (tid == 0)
            __hip_atomic_store(&flags[w], nb, __ATOMIC_RELAXED,
                               __HIP_MEMORY_SCOPE_SYSTEM);
    };
    auto wait_bar = [&]() {
        if (wave == 0) {
            const int tgt = nb;
            int iter = 0;
            for (;;) {
                int f0 = __hip_atomic_load(&flags[lane], __ATOMIC_RELAXED,
                                           __HIP_MEMORY_SCOPE_SYSTEM);
                int f1 = __hip_atomic_load(&flags[64 + lane], __ATOMIC_RELAXED,
                                           __HIP_MEMORY_SCOPE_SYSTEM);
                if (__all(f0 >= tgt && f1 >= tgt)) break;
                if (++iter > 65536) break;   // safety net
                __builtin_amdgcn_s_sleep(1);
            }
        }
        __syncthreads();         // no fence: cross-step reads are sc0+sc1
    };

    // epilogue-only LN stats (per-step stats are computed inline in phase 0)
    auto ln_stats = [&]() {
        const int row = tid & 127, q = tid >> 7;
        const unsigned* hp = &H1p[row * 512 + q * 128];
        float s = 0.f, s2 = 0.f;
        #pragma unroll
        for (int c = 0; c < 2; ++c) {
            uint32x4 sb[16];
            #pragma unroll
            for (int i = 0; i < 16; ++i)
                sb[i] = llc_ld4(hp + c * 64 + i * 4);
            llc_wait0();
            #pragma unroll
            for (int i = 0; i < 16; ++i) {
                #pragma unroll
                for (int e = 0; e < 4; ++e) {
                    const float v = unpack2f(sb[i][e]);
                    s  += v;
                    s2 += v * v;
                }
            }
        }
        gbuf[row][q * 2]     = s;
        gbuf[row][q * 2 + 1] = s2;
        __syncthreads();
        if (tid < 128) {
            const float ss  = gbuf[tid][0] + gbuf[tid][2] + gbuf[tid][4] + gbuf[tid][6];
            const float ss2 = gbuf[tid][1] + gbuf[tid][3] + gbuf[tid][5] + gbuf[tid][7];
            const float mu  = ss * (1.0f / 512.0f);
            const float var = ss2 * (1.0f / 512.0f) - mu * mu;
            const float rs  = rsqrtf(var + 1e-5f);
            rs_s[tid]   = rs;
            murs_s[tid] = mu * rs;
        }
        __syncthreads();
    };

    // materialize LN'd bf16 rows (4 rows for WGs 0..31) into Hnb slot
    unsigned* Hnb32 = (unsigned*)Hnb;
    auto mat_slot = [&](int slot) {
        const int rb = w * 4;
        const int p0 = tid, p1 = tid + 512;          // pair indices [0,1024)
        const int m0r = rb + (p0 >> 8), k0 = (p0 & 255) * 2;
        const int m1r = rb + (p1 >> 8), k1 = (p1 & 255) * 2;
        uint32x2 a = llc_ld2(&H1p[m0r * 512 + k0]);
        uint32x2 b = llc_ld2(&H1p[m1r * 512 + k1]);
        llc_wait0();
        {
            const float v0 = unpack2f(a[0]), v1 = unpack2f(a[1]);
            const float o0 = fmaf(fmaf(v0, rs_s[m0r], -murs_s[m0r]), gam_s[k0],     bet_s[k0]);
            const float o1 = fmaf(fmaf(v1, rs_s[m0r], -murs_s[m0r]), gam_s[k0 + 1], bet_s[k0 + 1]);
            const unsigned pk = (unsigned)(unsigned short)f2bf_rne(o0)
                              | ((unsigned)(unsigned short)f2bf_rne(o1) << 16);
            llc_stu(&Hnb32[((long)slot * B_ + m0r) * 256 + (p0 & 255)], pk);
        }
        {
            const float v0 = unpack2f(b[0]), v1 = unpack2f(b[1]);
            const float o0 = fmaf(fmaf(v0, rs_s[m1r], -murs_s[m1r]), gam_s[k1],     bet_s[k1]);
            const float o1 = fmaf(fmaf(v1, rs_s[m1r], -murs_s[m1r]), gam_s[k1 + 1], bet_s[k1 + 1]);
            const unsigned pk = (unsigned)(unsigned short)f2bf_rne(o0)
                              | ((unsigned)(unsigned short)f2bf_rne(o1) << 16);
            llc_stu(&Hnb32[((long)slot * B_ + m1r) * 256 + (p1 & 255)], pk);
        }
    };

    const int rA0 = (wm + n) * 512;
    const int rq  = (lane >> 4) * 4;

    for (int t = 0; t < T_; ++t) {
        const short* xh = Xhi + (long)t * B_ * D_;
        const short* xl = Xlo + (long)t * B_ * D_;

        // ================= phase 0 (layer 0) =================
        {
            f32x4 accx = {0.f, 0.f, 0.f, 0.f};
            f32x4 acch = {0.f, 0.f, 0.f, 0.f};
            // x-half: L2-warm cached loads, runs while the barrier propagates
            #pragma unroll 4
            for (int kc = 0; kc < 16; ++kc) {
                const int kg = kc * 32 + kq;
                short8 bh = *(const short8*)&Wh[0][n][kg];
                short8 bl = *(const short8*)&Wo[0][n][kg];
                short8 ah = *(const short8*)&xh[rA0 + kg];
                short8 al = *(const short8*)&xl[rA0 + kg];
                accx = __builtin_amdgcn_mfma_f32_16x16x32_bf16(ah, bh, accx, 0, 0, 0);
                accx = __builtin_amdgcn_mfma_f32_16x16x32_bf16(ah, bl, accx, 0, 0, 0);
                accx = __builtin_amdgcn_mfma_f32_16x16x32_bf16(al, bh, accx, 0, 0, 0);
            }
            if (t > 0) {
                wait_bar();          // H1p(t-1) at the LLC; vmcnt drained to 0
                // 32-deep pipelined LLC loads of this wave's h rows
                uint32x4 hb0[16], hb1[16];
                #pragma unroll
                for (int i = 0; i < 8; ++i) {
                    const int kh = i * 32 + kq;
                    hb0[i * 2]     = llc_ld4(&H1p[rA0 + kh]);
                    hb0[i * 2 + 1] = llc_ld4(&H1p[rA0 + kh + 4]);
                }
                #pragma unroll
                for (int i = 0; i < 8; ++i) {
                    const int kh = (8 + i) * 32 + kq;
                    hb1[i * 2]     = llc_ld4(&H1p[rA0 + kh]);
                    hb1[i * 2 + 1] = llc_ld4(&H1p[rA0 + kh + 4]);
                }
                float s = 0.f, s2 = 0.f;
                llc_wait16();        // batch0 done; batch1 in flight
                #pragma unroll
                for (int i = 0; i < 8; ++i) {
                    const int kh = i * 32 + kq;
                    short8 bh = *(const short8*)&Wh[0][n][512 + kh];
                    short8 bl = *(const short8*)&Wo[0][n][512 + kh];
                    unsigned u[8];
                    *(uint32x4*)&u[0] = hb0[i * 2];
                    *(uint32x4*)&u[4] = hb0[i * 2 + 1];
                    short8 ah, al;
                    #pragma unroll
                    for (int j = 0; j < 8; ++j) {
                        ah[j] = (short)(u[j] & 0xFFFFu);
                        al[j] = (short)(u[j] >> 16);
                        const float v = unpack2f(u[j]);
                        s  += v;
                        s2 += v * v;
                    }
                    acch = __builtin_amdgcn_mfma_f32_16x16x32_bf16(ah, bh, acch, 0, 0, 0);
                    acch = __builtin_amdgcn_mfma_f32_16x16x32_bf16(ah, bl, acch, 0, 0, 0);
                    acch = __builtin_amdgcn_mfma_f32_16x16x32_bf16(al, bh, acch, 0, 0, 0);
                }
                llc_wait0();         // batch1 done
                #pragma unroll
                for (int i = 0; i < 8; ++i) {
                    const int kh = (8 + i) * 32 + kq;
                    short8 bh = *(const short8*)&Wh[0][n][512 + kh];
                    short8 bl = *(const short8*)&Wo[0][n][512 + kh];
                    unsigned u[8];
                    *(uint32x4*)&u[0] = hb1[i * 2];
                    *(uint32x4*)&u[4] = hb1[i * 2 + 1];
                    short8 ah, al;
                    #pragma unroll
                    for (int j = 0; j < 8; ++j) {
                        ah[j] = (short)(u[j] & 0xFFFFu);
                        al[j] = (short)(u[j] >> 16);
                        const float v = unpack2f(u[j]);
                        s  += v;
                        s2 += v * v;
                    }
                    acch = __builtin_amdgcn_mfma_f32_16x16x32_bf16(ah, bh, acch, 0, 0, 0);
                    acch = __builtin_amdgcn_mfma_f32_16x16x32_bf16(ah, bl, acch, 0, 0, 0);
                    acch = __builtin_amdgcn_mfma_f32_16x16x32_bf16(al, bh, acch, 0, 0, 0);
                }
                // inline LN stats: 4 kq-lanes of same n cover all 512 cols
                // of row wm+n -> reduce across lanes {n, n+16, n+32, n+48}
                s  += __shfl_xor(s, 16);  s  += __shfl_xor(s, 32);
                s2 += __shfl_xor(s2, 16); s2 += __shfl_xor(s2, 32);
                if (lane < 16) {
                    const float mu  = s * (1.0f / 512.0f);
                    const float var = s2 * (1.0f / 512.0f) - mu * mu;
                    const float rs  = rsqrtf(var + 1e-5f);
                    rs_s[wm + lane]   = rs;
                    murs_s[wm + lane] = mu * rs;
                }
                __syncthreads();     // rs/murs visible cross-wave (mat_slot)
                if (w < 32 && t >= 2) mat_slot(t - 2);
            }
            const float bs = bias_s[0][n] + (t > 0 ? bconst_s[n] : 0.f);
            const float sg = sgam_s[n];
            #pragma unroll
            for (int r = 0; r < 4; ++r) {
                const int row = wm + rq + r;
                float g = accx[r] + bs;
                if (t > 0) g += acch[r] * rs_s[row] - murs_s[row] * sg;
                gbuf[row][n] = g;
            }
            __syncthreads();
            {
                const int m = tid >> 2, d = tid & 3;
                const float gi = gbuf[m][d],     gf = gbuf[m][4 + d];
                const float gg = gbuf[m][8 + d], go = gbuf[m][12 + d];
                const float cn = sigm(gf) * carr[m][d] + sigm(gi) * tanhf(gg);
                carr[m][d] = cn;
                const float hv = sigm(go) * tanhf(cn);
                short hi_, lo_;
                split2(hv, hi_, lo_);
                const unsigned pk = (unsigned)(unsigned short)hi_
                                  | ((unsigned)(unsigned short)lo_ << 16);
                llc_stu(&H0p[m * 512 + d0 + d], pk);
            }
            arrive();   // barrier 2t+1: publish H0(t) (+ Hnb slot t-2)
        }

        // ================= phase 1 (layer 1) =================
        {
            f32x4 acc = {0.f, 0.f, 0.f, 0.f};
            #pragma unroll 4
            for (int kc = 0; kc < 16; ++kc) {
                const int kg = kc * 32 + kq;
                short8 bh = *(const short8*)&Wh[1][n][kg];
                short8 bl = *(const short8*)&Wo[1][n][kg];
                short8 ah = *(const short8*)&xh[rA0 + kg];
                short8 al = *(const short8*)&xl[rA0 + kg];
                acc = __builtin_amdgcn_mfma_f32_16x16x32_bf16(ah, bh, acc, 0, 0, 0);
                acc = __builtin_amdgcn_mfma_f32_16x16x32_bf16(ah, bl, acc, 0, 0, 0);
                acc = __builtin_amdgcn_mfma_f32_16x16x32_bf16(al, bh, acc, 0, 0, 0);
            }
            wait_bar();   // H0p(t) at the LLC; vmcnt drained to 0
            {
                uint32x4 hb0[16], hb1[16];
                #pragma unroll
                for (int i = 0; i < 8; ++i) {
                    const int kh = i * 32 + kq;
                    hb0[i * 2]     = llc_ld4(&H0p[rA0 + kh]);
                    hb0[i * 2 + 1] = llc_ld4(&H0p[rA0 + kh + 4]);
                }
                #pragma unroll
                for (int i = 0; i < 8; ++i) {
                    const int kh = (8 + i) * 32 + kq;
                    hb1[i * 2]     = llc_ld4(&H0p[rA0 + kh]);
                    hb1[i * 2 + 1] = llc_ld4(&H0p[rA0 + kh + 4]);
                }
                llc_wait16();
                #pragma unroll
                for (int i = 0; i < 8; ++i) {
                    const int kh = i * 32 + kq;
                    short8 bh = *(const short8*)&Wh[1][n][512 + kh];
                    short8 bl = *(const short8*)&Wo[1][n][512 + kh];
                    unsigned u[8];
                    *(uint32x4*)&u[0] = hb0[i * 2];
                    *(uint32x4*)&u[4] = hb0[i * 2 + 1];
                    short8 ah, al;
                    #pragma unroll
                    for (int j = 0; j < 8; ++j) {
                        ah[j] = (short)(u[j] & 0xFFFFu);
                        al[j] = (short)(u[j] >> 16);
                    }
                    acc = __builtin_amdgcn_mfma_f32_16x16x32_bf16(ah, bh, acc, 0, 0, 0);
                    acc = __builtin_amdgcn_mfma_f32_16x16x32_bf16(ah, bl, acc, 0, 0, 0);
                    acc = __builtin_amdgcn_mfma_f32_16x16x32_bf16(al, bh, acc, 0, 0, 0);
                }
                llc_wait0();
                #pragma unroll
                for (int i = 0; i < 8; ++i) {
                    const int kh = (8 + i) * 32 + kq;
                    short8 bh = *(const short8*)&Wh[1][n][512 + kh];
                    short8 bl = *(const short8*)&Wo[1][n][512 + kh];
                    unsigned u[8];
                    *(uint32x4*)&u[0] = hb1[i * 2];
                    *(uint32x4*)&u[4] = hb1[i * 2 + 1];
                    short8 ah, al;
                    #pragma unroll
                    for (int j = 0; j < 8; ++j) {
                        ah[j] = (short)(u[j] & 0xFFFFu);
                        al[j] = (short)(u[j] >> 16);
                    }
                    acc = __builtin_amdgcn_mfma_f32_16x16x32_bf16(ah, bh, acc, 0, 0, 0);
                    acc = __builtin_amdgcn_mfma_f32_16x16x32_bf16(ah, bl, acc, 0, 0, 0);
                    acc = __builtin_amdgcn_mfma_f32_16x16x32_bf16(al, bh, acc, 0, 0, 0);
                }
            }
            const float bs = bias_s[1][n];
            #pragma unroll
            for (int r = 0; r < 4; ++r)
                gbuf[wm + rq + r][n] = acc[r] + bs;
            __syncthreads();
            {
                const int m = tid >> 2, d = tid & 3;
                const float gi = gbuf[m][d],     gf = gbuf[m][4 + d];
                const float gg = gbuf[m][8 + d], go = gbuf[m][12 + d];
                const float cn = sigm(gf) * carr[m][d] + sigm(gi) * tanhf(gg);
                carr[m][d] = cn;
                const float hv = sigm(go) * tanhf(cn);
                short hi_, lo_;
                split2(hv, hi_, lo_);
                const unsigned pk = (unsigned)(unsigned short)hi_
                                  | ((unsigned)(unsigned short)lo_ << 16);
                llc_stu(&H1p[m * 512 + d0 + d], pk);   // RAW h1, packed
            }
            arrive();   // barrier 2t+2: publish H1p(t)
        }
    }

    // epilogue: final FC row block = LN(h1(T-1)) -> slot L_-1, then publish
    wait_bar();
    ln_stats();
    if (w < 32) mat_slot(L_ - 1);
    arrive();   // flags -> 67 = 2*31+5: unblocks helper tiles for slot 31
}

// ---------------------------------------------------------------------------
// log-softmax, 2 passes (|logits| <= ~35 so exp-sum is fp32-safe w/o shift)
// ---------------------------------------------------------------------------
__global__ void logsoftmax_kernel(float* __restrict__ out) {
    __shared__ float red[256];
    const long row = blockIdx.x;
    float* p = out + row * V_;
    float4* p4 = reinterpret_cast<float4*>(p);
    const int tid = threadIdx.x;
    float s = 0.f;
    for (int i = tid; i < V_ / 4; i += 256) {
        float4 v = p4[i];
        s += __expf(v.x) + __expf(v.y) + __expf(v.z) + __expf(v.w);
    }
    red[tid] = s;
    __syncthreads();
    for (int st = 128; st > 0; st >>= 1) {
        if (tid < st) red[tid] += red[tid + st];
        __syncthreads();
    }
    const float ls = logf(red[0]);
    for (int i = tid; i < V_ / 4; i += 256) {
        float4 v = p4[i];
        v.x -= ls; v.y -= ls; v.z -= ls; v.w -= ls;
        p4[i] = v;
    }
}

// ---------------------------------------------------------------------------
extern "C" void kernel_launch(void* const* d_in, const int* in_sizes, int n_in,
                              void* d_out, int out_size, void* d_ws, size_t ws_size,
                              hipStream_t stream) {
    const float* features = (const float*)d_in[0];
    const int*   caption  = (const int*)d_in[1];
    const float* embW     = (const float*)d_in[2];
    const float* W_ih     = (const float*)d_in[3];
    const float* W_hh     = (const float*)d_in[4];
    const float* b_ih     = (const float*)d_in[5];
    const float* b_hh     = (const float*)d_in[6];
    const float* ln_g     = (const float*)d_in[7];
    const float* ln_b     = (const float*)d_in[8];
    const float* fc_W     = (const float*)d_in[9];
    const float* fc_b     = (const float*)d_in[10];
    float* out = (float*)d_out;

    char* ws = (char*)d_ws;
    int*      syncv = (int*)ws;      ws += 512;                        // 128 flags
    short*    Xhi   = (short*)ws;    ws += (size_t)T_ * B_ * D_ * 2;   // 4,325,376
    short*    Xlo   = (short*)ws;    ws += (size_t)T_ * B_ * D_ * 2;
    unsigned* H0p   = (unsigned*)ws; ws += (size_t)B_ * D_ * 4;        // 262,144
    unsigned* H1p   = (unsigned*)ws; ws += (size_t)B_ * D_ * 4;        // 262,144
    short*    Hnb   = (short*)ws;    ws += (size_t)L_ * B_ * D_ * 2;   // 4,194,304
    short*    fcWb  = (short*)ws;    ws += (size_t)V_ * D_ * 2;        // 10,240,000

    prep_kernel<<<2048, 256, 0, stream>>>(features, caption, embW, fc_W,
                                          Xhi, Xlo, fcWb, syncv);

    lstm_persist<<<NWG + NHELP, THREADS, 0, stream>>>(
        Xhi, Xlo, W_ih, W_hh, b_ih, b_hh, ln_g, ln_b,
        H0p, H1p, Hnb, syncv, fcWb, fc_b, out);

    logsoftmax_kernel<<<4096, 256, 0, stream>>>(out);
}